// Round 6
// baseline (174.524 us; speedup 1.0000x reference)
//
#include <hip/hip_runtime.h>

// Triaffine span[b,x,y,z] = sum_{i,o,j} start[b,x,i] W[i,o,j] end[b,y,j] cls[b,z,o]
// B=8, L=256, Z=16, H=256. Contraction order o -> i -> j (12.9 GF), bf16 MFMA.
//   K0: endbf = bf16(end)                               (1MB, ~2us)
//   K1: Wc[bz,i,j]  = sum_o cls[bz,o] * W[i,o,j]        batch=i  (W TRANS-staged)
//   K2: T [bz,x,j]  = sum_i start[b,x,i] * Wc[bz,i,j]   batch=bz (Wc TRANS-staged)
//   K3': out[b,x,y,z] = sum_j endbf[b,y,j] * T[(b,z),x,j]
//        fused GEMM M=y(256) N=z(16!) K=j(256), LDS-free, barrier-free,
//        z = MFMA N-fragment lane (lr) -> fully coalesced out writes.
// (Round-6 = round-5 resubmit; round-5 never ran: GPU acquisition timeout.)
//  * depth-2 prefetch register sets in K1/K2 (r4's depth-1 was consumed in the
//    same iteration -> vmcnt drain every step; now covered by a full step).
//  * TRANS LDS-write index split: kp from low lane bits (even-bank 4-way max).
//  * K3+K4 fused (kills tmp: -134MB HBM, -1 launch); T moved to d_ws.
// ws layout: Wc bf16 @0 (16.8MB); T bf16 @16.8MB; endbf @33.6MB. ~34.6MB total.

typedef __attribute__((ext_vector_type(8))) short          bf16x8;
typedef __attribute__((ext_vector_type(8))) unsigned short u16x8;
typedef __attribute__((ext_vector_type(4))) unsigned short u16x4;
typedef __attribute__((ext_vector_type(4))) float          f32x4;

#define LDST 40   // LDS row stride in shorts (80B rows: 16B-aligned, 2-way read banks)

__device__ __forceinline__ unsigned short f2bf(float f) {
    unsigned u = __builtin_bit_cast(unsigned, f);
    u += 0x7fff + ((u >> 16) & 1);            // RNE
    return (unsigned short)(u >> 16);
}

// 128x128 tile, K=256 (8 steps of BK=32), 512 threads = 8 waves (4m x 2n, 32x64 each).
// A: fp32 [m][k] row-major. B: BB16? bf16 : fp32, [k][n] (TRANS-staged into LDS [n][k]).
template<bool BB16>
__global__ __launch_bounds__(512, 4)
void gemm_trans(const float* __restrict__ Ab, const void* __restrict__ Bbv,
                unsigned short* __restrict__ Cb,
                int lda, int ldb, int ldc,
                long aBS, int aSh, long bBS, long cBS)
{
    __shared__ unsigned short As[2][128 * LDST];
    __shared__ unsigned short Bs[2][128 * LDST];

    const int tid  = threadIdx.x;
    const int bz   = blockIdx.z;
    const int row0 = blockIdx.y * 128;
    const int col0 = blockIdx.x * 128;

    const float*          Af = Ab + (long)(bz >> aSh) * aBS;
    const float*          Bf = (const float*)Bbv          + (long)bz * bBS;
    const unsigned short* Bh = (const unsigned short*)Bbv + (long)bz * bBS;
    unsigned short*       C  = Cb + (long)bz * cBS;

    // staging indices
    const int ar  = tid >> 2;         // 0..127 A row
    const int akc = tid & 3;          // A k-chunk of 8
    const int kp  = (tid & 15) * 2;   // B k-row pair 0..30  (low bits -> bounded bank fan)
    const int ng  = (tid >> 4) * 4;   // B n group of 4, 0..124

    // compute indices
    const int wid = tid >> 6, lane = tid & 63;
    const int wm = wid >> 1, wn = wid & 1;        // 4 m-waves x 2 n-waves
    const int lr = lane & 15, lg = lane >> 4;

    f32x4 acc[2][4] = {};

    // depth-2 prefetch sets
    float4 aP[2][2];
    float4 bPf[2][2];
    u16x4  bPh[2][2];

    auto LOAD = [&](int set, int k0) {
        const float* p = Af + (long)(row0 + ar) * lda + k0 + akc * 8;
        aP[set][0] = *(const float4*)p;
        aP[set][1] = *(const float4*)(p + 4);
        if constexpr (!BB16) {
            const float* q = Bf + (long)(k0 + kp) * ldb + col0 + ng;
            bPf[set][0] = *(const float4*)q;
            bPf[set][1] = *(const float4*)(q + ldb);
        } else {
            const unsigned short* q = Bh + (long)(k0 + kp) * ldb + col0 + ng;
            bPh[set][0] = *(const u16x4*)q;
            bPh[set][1] = *(const u16x4*)(q + ldb);
        }
    };

    auto WRITE = [&](int set, int buf) {
        u16x8 w;
        const float* v = (const float*)&aP[set][0];
#pragma unroll
        for (int e = 0; e < 8; ++e) w[e] = f2bf(v[e]);
        *(u16x8*)(As[buf] + ar * LDST + akc * 8) = w;

#pragma unroll
        for (int e = 0; e < 4; ++e) {
            unsigned lo, hi;
            if constexpr (!BB16) {
                const float* v0 = (const float*)&bPf[set][0];
                const float* v1 = (const float*)&bPf[set][1];
                lo = f2bf(v0[e]); hi = f2bf(v1[e]);
            } else {
                lo = bPh[set][0][e]; hi = bPh[set][1][e];
            }
            *(unsigned*)(Bs[buf] + (ng + e) * LDST + kp) = lo | (hi << 16);
        }
    };

    auto COMPUTE = [&](int buf) {
        bf16x8 aF[2], bF[4];
#pragma unroll
        for (int fm = 0; fm < 2; ++fm)
            aF[fm] = *(const bf16x8*)&As[buf][(wm * 32 + fm * 16 + lr) * LDST + lg * 8];
#pragma unroll
        for (int fn = 0; fn < 4; ++fn)
            bF[fn] = *(const bf16x8*)&Bs[buf][(wn * 64 + fn * 16 + lr) * LDST + lg * 8];
#pragma unroll
        for (int fm = 0; fm < 2; ++fm)
#pragma unroll
            for (int fn = 0; fn < 4; ++fn)
                acc[fm][fn] = __builtin_amdgcn_mfma_f32_16x16x32_bf16(
                    aF[fm], bF[fn], acc[fm][fn], 0, 0, 0);
    };

    LOAD(0, 0);
    WRITE(0, 0);        // one-time vmcnt stall; fills buf0
    LOAD(1, 32);        // set1 in flight across iter0
#pragma unroll
    for (int s = 0; s < 8; ++s) {
        asm volatile("s_waitcnt lgkmcnt(0)" ::: "memory");  // own ds ops drained
        __builtin_amdgcn_s_barrier();                       // no vmcnt drain
        if (s < 6) LOAD(s & 1, (s + 2) * 32);               // refill freed set
        COMPUTE(s & 1);
        if (s < 7) WRITE((s + 1) & 1, (s + 1) & 1);         // set loaded 1 step ago
    }

    // epilogue: C/D mapping col=lane&15, row=(lane>>4)*4+q  [m89-verified]
#pragma unroll
    for (int fm = 0; fm < 2; ++fm)
#pragma unroll
        for (int q = 0; q < 4; ++q) {
            const long row = row0 + wm * 32 + fm * 16 + lg * 4 + q;
#pragma unroll
            for (int fn = 0; fn < 4; ++fn) {
                const int col = col0 + wn * 64 + fn * 16 + lr;
                C[row * (long)ldc + col] = f2bf(acc[fm][fn][q]);
            }
        }
}

// Fused stage-3: out[b,x,y,z] = sum_j endbf[b,y,j] * T[(b,z),x,j]
// One block per (b,x); 4 waves, wave w covers y in [w*64, w*64+64).
// M=y(256) N=z(16, one fragment: z=lr) K=j(256). No LDS, no barriers.
__global__ __launch_bounds__(256)
void fused_out(const unsigned short* __restrict__ endbf,
               const unsigned short* __restrict__ T,
               float* __restrict__ out)
{
    const int tid = threadIdx.x;
    const int b = blockIdx.x >> 8;
    const int x = blockIdx.x & 255;
    const int wid = tid >> 6, lane = tid & 63;
    const int lr = lane & 15, lg = lane >> 4;

    const unsigned short* Arow = endbf + (long)b * 65536;                   // [y][j]
    const unsigned short* Bcol = T + (long)(b * 16 + lr) * 65536 + x * 256; // [z=lr][j]

    f32x4 acc[4] = {};
    u16x8 a[2][4], bb[2];

    auto LOADF = [&](int set, int k0) {
#pragma unroll
        for (int fm = 0; fm < 4; ++fm)
            a[set][fm] = *(const u16x8*)(Arow + (long)(wid * 64 + fm * 16 + lr) * 256 + k0 + lg * 8);
        bb[set] = *(const u16x8*)(Bcol + k0 + lg * 8);
    };

    LOADF(0, 0);
#pragma unroll
    for (int s = 0; s < 8; ++s) {
        if (s < 7) LOADF((s + 1) & 1, (s + 1) * 32);
#pragma unroll
        for (int fm = 0; fm < 4; ++fm)
            acc[fm] = __builtin_amdgcn_mfma_f32_16x16x32_bf16(
                __builtin_bit_cast(bf16x8, a[s & 1][fm]),
                __builtin_bit_cast(bf16x8, bb[s & 1]), acc[fm], 0, 0, 0);
    }

    // C[m=y][n=z]: y = wid*64 + fm*16 + lg*4 + q, z = lr. out fully coalesced.
    float* op = out + (long)(b * 256 + x) * 4096;
#pragma unroll
    for (int fm = 0; fm < 4; ++fm)
#pragma unroll
        for (int q = 0; q < 4; ++q)
            op[(wid * 64 + fm * 16 + lg * 4 + q) * 16 + lr] = acc[fm][q];
}

// end fp32 -> bf16 (524288 elems, 8/thread)
__global__ __launch_bounds__(256)
void cvt_bf16(const float* __restrict__ in, unsigned short* __restrict__ out)
{
    const int i = (blockIdx.x * 256 + threadIdx.x) * 8;
    float4 v0 = *(const float4*)(in + i);
    float4 v1 = *(const float4*)(in + i + 4);
    const float* v = (const float*)&v0;
    u16x8 w;
#pragma unroll
    for (int e = 0; e < 4; ++e) w[e] = f2bf(v[e]);
    const float* u = (const float*)&v1;
#pragma unroll
    for (int e = 0; e < 4; ++e) w[4 + e] = f2bf(u[e]);
    *(u16x8*)(out + i) = w;
}

extern "C" void kernel_launch(void* const* d_in, const int* in_sizes, int n_in,
                              void* d_out, int out_size, void* d_ws, size_t ws_size,
                              hipStream_t stream)
{
    const float* start = (const float*)d_in[0];  // [8,256,256]
    const float* endl  = (const float*)d_in[1];  // [8,256,256]
    const float* cls   = (const float*)d_in[2];  // [8,16,256] -> [128][256]
    const float* W     = (const float*)d_in[3];  // [256,256,256] (i,o,j)
    float* out = (float*)d_out;                  // [8,256,256,16]

    char* ws = (char*)d_ws;
    unsigned short* Wc    = (unsigned short*)ws;                // bf16 [128][256][256] 16.8MB
    unsigned short* T     = (unsigned short*)(ws + 16777216);   // bf16 [128][256][256] 16.8MB
    unsigned short* endbf = (unsigned short*)(ws + 33554432);   // bf16 [8][256][256]    1MB

    // K0: end -> bf16
    hipLaunchKernelGGL(cvt_bf16, dim3(256), dim3(256), 0, stream, endl, endbf);

    // K1: Wc[bz,i,j] = sum_o cls[bz,o]*W[i,o,j].  batch=i(256). M=128(bz),N=256(j),K=256(o)
    //     A=cls (shared, lda=256); B=W+i*65536 fp32 [o][j]; C=Wc+i*256 (ldc=65536, row=bz)
    hipLaunchKernelGGL((gemm_trans<false>), dim3(2, 1, 256), dim3(512), 0, stream,
        cls, (const void*)W, Wc, 256, 256, 65536, 0L, 0, 65536L, 256L);

    // K2: T[bz,x,j] = sum_i start[b,x,i]*Wc[bz,i,j].  batch=bz(128). M=N=K=256
    hipLaunchKernelGGL((gemm_trans<true>), dim3(2, 2, 128), dim3(512), 0, stream,
        start, (const void*)Wc, T, 256, 256, 256, 65536L, 4, 65536L, 65536L);

    // K3': fused out
    hipLaunchKernelGGL(fused_out, dim3(2048), dim3(256), 0, stream, endbf, T, out);
}

// Round 7
// 158.603 us; speedup vs baseline: 1.1004x; 1.1004x over previous
//
#include <hip/hip_runtime.h>

// Triaffine span[b,x,y,z] = sum_{i,o,j} start[b,x,i] W[i,o,j] end[b,y,j] cls[b,z,o]
// B=8, L=256, Z=16, H=256. Contraction order o -> i -> j (12.9 GF), bf16 MFMA.
//   K0: endbf = bf16(end), startbf = bf16(start)
//   K1: Wc[bz,i,j]  = sum_o cls[bz,o] * W[i,o,j]        batch=i  (W TRANS-staged)
//   K2: T2[b,x,z,j] = sum_i startbf[b,x,i] * Wc[bz,i,j] batch=bz (Wc TRANS-staged)
//       NOTE T2 layout: z-rows contiguous per (b,x) -> fused B-reads are one 8KB block.
//   K3': out[b,x,y,z] = sum_j endbf[b,y,j] * T2[b,x,z,j]
//        2 x's per block, A-frags (endbf) reused across both -> 2x MFMA density.
// Round-7 vs round-6 (174us: fill 41 + K0 2 + K1 ~40 + K2 ~45 + fused 43):
//  * fused_out was latency-sick (Mfma 3.3%, VALU 1.5%, HBM 13%): its B-loads hit
//    16 z-rows strided 128KB (cross-XCD L2 misses). T2 layout makes them one
//    contiguous 8KB L1-resident block; 2-x blocks halve A traffic; setprio(1).
//  * K2 A-operand pre-converted to bf16 in K0 (identical numerics, half A bytes,
//    no f2bf in K2 staging).
// ws: Wc @0 (16.8MB); T2 @16.8MB (16.8MB); endbf @33.6MB (1MB); startbf @34.6MB (1MB).

typedef __attribute__((ext_vector_type(8))) short          bf16x8;
typedef __attribute__((ext_vector_type(8))) unsigned short u16x8;
typedef __attribute__((ext_vector_type(4))) unsigned short u16x4;
typedef __attribute__((ext_vector_type(4))) float          f32x4;

#define LDST 40   // LDS row stride in shorts (80B rows: 16B-aligned)

__device__ __forceinline__ unsigned short f2bf(float f) {
    unsigned u = __builtin_bit_cast(unsigned, f);
    u += 0x7fff + ((u >> 16) & 1);            // RNE
    return (unsigned short)(u >> 16);
}

// 128x128 tile, K=256 (8 steps of BK=32), 512 threads = 8 waves (4m x 2n, 32x64 each).
// A: [m][k] row-major (AB16? bf16 : fp32). B: [k][n] (BB16? bf16 : fp32), TRANS-staged.
// T2OUT: epilogue writes T2[b][x][z][j] (bz = batch) instead of C + bz*cBS.
template<bool AB16, bool BB16, bool T2OUT>
__global__ __launch_bounds__(512, 4)
void gemm_trans(const void* __restrict__ Abv, const void* __restrict__ Bbv,
                unsigned short* __restrict__ Cb,
                int lda, int ldb, int ldc,
                long aBS, int aSh, long bBS, long cBS)
{
    __shared__ unsigned short As[2][128 * LDST];
    __shared__ unsigned short Bs[2][128 * LDST];

    const int tid  = threadIdx.x;
    const int bz   = blockIdx.z;
    const int row0 = blockIdx.y * 128;
    const int col0 = blockIdx.x * 128;

    const float*          Af = (const float*)Abv          + (long)(bz >> aSh) * aBS;
    const unsigned short* Ah = (const unsigned short*)Abv + (long)(bz >> aSh) * aBS;
    const float*          Bf = (const float*)Bbv          + (long)bz * bBS;
    const unsigned short* Bh = (const unsigned short*)Bbv + (long)bz * bBS;

    // staging indices
    const int ar  = tid >> 2;         // 0..127 A row
    const int akc = tid & 3;          // A k-chunk of 8
    const int kp  = (tid & 15) * 2;   // B k-row pair 0..30 (low bits: bounded bank fan)
    const int ng  = (tid >> 4) * 4;   // B n group of 4, 0..124

    // compute indices
    const int wid = tid >> 6, lane = tid & 63;
    const int wm = wid >> 1, wn = wid & 1;        // 4 m-waves x 2 n-waves
    const int lr = lane & 15, lg = lane >> 4;

    f32x4 acc[2][4] = {};

    // depth-2 prefetch sets
    float4 aPf[2][2]; u16x8 aPh[2];
    float4 bPf[2][2]; u16x4 bPh[2][2];

    auto LOAD = [&](int set, int k0) {
        if constexpr (!AB16) {
            const float* p = Af + (long)(row0 + ar) * lda + k0 + akc * 8;
            aPf[set][0] = *(const float4*)p;
            aPf[set][1] = *(const float4*)(p + 4);
        } else {
            aPh[set] = *(const u16x8*)(Ah + (long)(row0 + ar) * lda + k0 + akc * 8);
        }
        if constexpr (!BB16) {
            const float* q = Bf + (long)(k0 + kp) * ldb + col0 + ng;
            bPf[set][0] = *(const float4*)q;
            bPf[set][1] = *(const float4*)(q + ldb);
        } else {
            const unsigned short* q = Bh + (long)(k0 + kp) * ldb + col0 + ng;
            bPh[set][0] = *(const u16x4*)q;
            bPh[set][1] = *(const u16x4*)(q + ldb);
        }
    };

    auto WRITE = [&](int set, int buf) {
        u16x8 w;
        if constexpr (!AB16) {
            const float* v = (const float*)&aPf[set][0];
#pragma unroll
            for (int e = 0; e < 8; ++e) w[e] = f2bf(v[e]);
        } else {
            w = aPh[set];
        }
        *(u16x8*)(As[buf] + ar * LDST + akc * 8) = w;

#pragma unroll
        for (int e = 0; e < 4; ++e) {
            unsigned lo, hi;
            if constexpr (!BB16) {
                const float* v0 = (const float*)&bPf[set][0];
                const float* v1 = (const float*)&bPf[set][1];
                lo = f2bf(v0[e]); hi = f2bf(v1[e]);
            } else {
                lo = bPh[set][0][e]; hi = bPh[set][1][e];
            }
            *(unsigned*)(Bs[buf] + (ng + e) * LDST + kp) = lo | (hi << 16);
        }
    };

    auto COMPUTE = [&](int buf) {
        bf16x8 aF[2], bF[4];
#pragma unroll
        for (int fm = 0; fm < 2; ++fm)
            aF[fm] = *(const bf16x8*)&As[buf][(wm * 32 + fm * 16 + lr) * LDST + lg * 8];
#pragma unroll
        for (int fn = 0; fn < 4; ++fn)
            bF[fn] = *(const bf16x8*)&Bs[buf][(wn * 64 + fn * 16 + lr) * LDST + lg * 8];
#pragma unroll
        for (int fm = 0; fm < 2; ++fm)
#pragma unroll
            for (int fn = 0; fn < 4; ++fn)
                acc[fm][fn] = __builtin_amdgcn_mfma_f32_16x16x32_bf16(
                    aF[fm], bF[fn], acc[fm][fn], 0, 0, 0);
    };

    LOAD(0, 0);
    WRITE(0, 0);        // one-time vmcnt stall; fills buf0
    LOAD(1, 32);        // set1 in flight across iter0
#pragma unroll
    for (int s = 0; s < 8; ++s) {
        asm volatile("s_waitcnt lgkmcnt(0)" ::: "memory");  // own ds ops drained
        __builtin_amdgcn_s_barrier();                       // no vmcnt drain
        if (s < 6) LOAD(s & 1, (s + 2) * 32);               // refill freed set
        COMPUTE(s & 1);
        if (s < 7) WRITE((s + 1) & 1, (s + 1) & 1);         // set loaded 1 step ago
    }

    // epilogue: C/D mapping col=lane&15, row=(lane>>4)*4+q  [m89-verified]
#pragma unroll
    for (int fm = 0; fm < 2; ++fm)
#pragma unroll
        for (int q = 0; q < 4; ++q) {
            const long row = row0 + wm * 32 + fm * 16 + lg * 4 + q;
#pragma unroll
            for (int fn = 0; fn < 4; ++fn) {
                const int col = col0 + wn * 64 + fn * 16 + lr;
                if constexpr (T2OUT) {
                    // T2[b][x=row][z=bz&15][j=col], b=bz>>4
                    unsigned short* Cq = Cb + (long)(bz >> 4) * 1048576 + (bz & 15) * 256;
                    Cq[row * 4096 + col] = f2bf(acc[fm][fn][q]);
                } else {
                    unsigned short* Cq = Cb + (long)bz * cBS;
                    Cq[row * (long)ldc + col] = f2bf(acc[fm][fn][q]);
                }
            }
        }
}

// Fused stage-3: out[b,x,y,z] = sum_j endbf[b,y,j] * T2[b,x,z,j]
// One block per (b, x-pair); 4 waves, wave w: y in [w*64, w*64+64).
// M=y(256) N=z(16, one fragment: z=lr) K=j(256). A-frags shared across both x.
__global__ __launch_bounds__(256)
void fused_out(const unsigned short* __restrict__ endbf,
               const unsigned short* __restrict__ T2,
               float* __restrict__ out)
{
    const int tid = threadIdx.x;
    const int b  = blockIdx.x >> 7;
    const int xp = blockIdx.x & 127;          // x-pair: x0=2*xp, x1=2*xp+1
    const int wid = tid >> 6, lane = tid & 63;
    const int lr = lane & 15, lg = lane >> 4;

    const unsigned short* Arow = endbf + (long)b * 65536;                    // [y][j]
    const unsigned short* B0 = T2 + ((long)(b * 256 + xp * 2) * 16 + lr) * 256; // [z=lr][j]
    const unsigned short* B1 = B0 + 4096;

    f32x4 acc0[4] = {}, acc1[4] = {};
    u16x8 a[2][4], pb0[2], pb1[2];

    auto LOADF = [&](int set, int k0) {
#pragma unroll
        for (int fm = 0; fm < 4; ++fm)
            a[set][fm] = *(const u16x8*)(Arow + (long)(wid * 64 + fm * 16 + lr) * 256 + k0 + lg * 8);
        pb0[set] = *(const u16x8*)(B0 + k0 + lg * 8);
        pb1[set] = *(const u16x8*)(B1 + k0 + lg * 8);
    };

    LOADF(0, 0);
#pragma unroll
    for (int s = 0; s < 8; ++s) {
        if (s < 7) LOADF((s + 1) & 1, (s + 1) * 32);
        __builtin_amdgcn_s_setprio(1);
#pragma unroll
        for (int fm = 0; fm < 4; ++fm) {
            acc0[fm] = __builtin_amdgcn_mfma_f32_16x16x32_bf16(
                __builtin_bit_cast(bf16x8, a[s & 1][fm]),
                __builtin_bit_cast(bf16x8, pb0[s & 1]), acc0[fm], 0, 0, 0);
            acc1[fm] = __builtin_amdgcn_mfma_f32_16x16x32_bf16(
                __builtin_bit_cast(bf16x8, a[s & 1][fm]),
                __builtin_bit_cast(bf16x8, pb1[s & 1]), acc1[fm], 0, 0, 0);
        }
        __builtin_amdgcn_s_setprio(0);
    }

    // D[m=y][n=z]: y = wid*64 + fm*16 + lg*4 + q, z = lr. out coalesced.
    float* op0 = out + (long)(b * 256 + xp * 2) * 4096;
    float* op1 = op0 + 4096;
#pragma unroll
    for (int fm = 0; fm < 4; ++fm)
#pragma unroll
        for (int q = 0; q < 4; ++q) {
            const int y = wid * 64 + fm * 16 + lg * 4 + q;
            op0[y * 16 + lr] = acc0[fm][q];
            op1[y * 16 + lr] = acc1[fm][q];
        }
}

// fp32 -> bf16: blocks 0..255 convert end, 256..511 convert start (524288 elems each)
__global__ __launch_bounds__(256)
void cvt_bf16(const float* __restrict__ endl, const float* __restrict__ start,
              unsigned short* __restrict__ endbf, unsigned short* __restrict__ startbf)
{
    const int which = blockIdx.x >> 8;
    const float* in = which ? start : endl;
    unsigned short* out = which ? startbf : endbf;
    const int i = ((blockIdx.x & 255) * 256 + threadIdx.x) * 8;
    float4 v0 = *(const float4*)(in + i);
    float4 v1 = *(const float4*)(in + i + 4);
    const float* v = (const float*)&v0;
    u16x8 w;
#pragma unroll
    for (int e = 0; e < 4; ++e) w[e] = f2bf(v[e]);
    const float* u = (const float*)&v1;
#pragma unroll
    for (int e = 0; e < 4; ++e) w[4 + e] = f2bf(u[e]);
    *(u16x8*)(out + i) = w;
}

extern "C" void kernel_launch(void* const* d_in, const int* in_sizes, int n_in,
                              void* d_out, int out_size, void* d_ws, size_t ws_size,
                              hipStream_t stream)
{
    const float* start = (const float*)d_in[0];  // [8,256,256]
    const float* endl  = (const float*)d_in[1];  // [8,256,256]
    const float* cls   = (const float*)d_in[2];  // [8,16,256] -> [128][256]
    const float* W     = (const float*)d_in[3];  // [256,256,256] (i,o,j)
    float* out = (float*)d_out;                  // [8,256,256,16]

    char* ws = (char*)d_ws;
    unsigned short* Wc      = (unsigned short*)ws;                // bf16 [128][256][256]
    unsigned short* T2      = (unsigned short*)(ws + 16777216);   // bf16 [8][256][16][256]
    unsigned short* endbf   = (unsigned short*)(ws + 33554432);   // bf16 [8][256][256]
    unsigned short* startbf = (unsigned short*)(ws + 34603008);   // bf16 [8][256][256]

    // K0: end, start -> bf16
    hipLaunchKernelGGL(cvt_bf16, dim3(512), dim3(256), 0, stream,
        endl, start, endbf, startbf);

    // K1: Wc[bz,i,j] = sum_o cls[bz,o]*W[i,o,j].  batch=i(256). M=128(bz),N=256(j),K=256(o)
    //     A=cls fp32 (shared); B=W+i*65536 fp32 [o][j]; C=Wc+i*256 (ldc=65536, row=bz)
    hipLaunchKernelGGL((gemm_trans<false, false, false>), dim3(2, 1, 256), dim3(512), 0, stream,
        (const void*)cls, (const void*)W, Wc, 256, 256, 65536, 0L, 0, 65536L, 256L);

    // K2: T2[b,x,z,j] = sum_i startbf[b,x,i]*Wc[bz,i,j].  batch=bz(128). M=N=K=256
    hipLaunchKernelGGL((gemm_trans<true, true, true>), dim3(2, 2, 128), dim3(512), 0, stream,
        (const void*)startbf, (const void*)Wc, T2, 256, 256, 4096, 65536L, 4, 65536L, 0L);

    // K3': fused out (1024 blocks: b x 128 x-pairs)
    hipLaunchKernelGGL(fused_out, dim3(1024), dim3(256), 0, stream, endbf, T2, out);
}

// Round 9
// 155.080 us; speedup vs baseline: 1.1254x; 1.0227x over previous
//
#include <hip/hip_runtime.h>

// Triaffine span[b,x,y,z] = sum_{i,o,j} start[b,x,i] W[i,o,j] end[b,y,j] cls[b,z,o]
// B=8, L=256, Z=16, H=256. Contraction order o -> i -> j (12.9 GF), bf16 MFMA.
//   K0: endbf/startbf/clsbf = bf16(...)
//   K1: Wc[bz,i,j]  = sum_o clsbf[bz,o] * W[i,o,j]      batch=i  (W TRANS-staged)
//   K2: T2[b,x,z,j] = sum_i startbf[b,x,i]*Wc[bz,i,j]   batch=bz (Wc TRANS-staged)
//   K3': out[b,x,y,z] = sum_j endbf[b,y,j] * T2[b,x,z,j]  (2 x's/block, z=N-frag)
// (Round-9 = round-8 resubmit; round-8 never ran: GPU acquisition timeout.)
//  * K1/K2 were phase-overhead-bound: BK=32 gave only 8 MFMA/wave between
//    barriers. Now BK=64 -> 4 phases, 16 MFMA + 24 ds_reads per phase, half the
//    barrier/drain cost; depth-2 prefetch spans a 2x longer window.
//  * cls pre-converted to bf16 (K1 A-staging is a pure copy, no f2bf).
//  * s_setprio(1) around MFMA clusters.
// ws: Wc @0 (16.8MB); T2 @16.8MB; endbf @33.6MB; startbf @34.6MB; clsbf @35.6MB.

typedef __attribute__((ext_vector_type(8))) short          bf16x8;
typedef __attribute__((ext_vector_type(8))) unsigned short u16x8;
typedef __attribute__((ext_vector_type(4))) float          f32x4;

#define LDST 72   // LDS row stride in shorts for BK=64 (144B rows, 16B-aligned)

__device__ __forceinline__ unsigned short f2bf(float f) {
    unsigned u = __builtin_bit_cast(unsigned, f);
    u += 0x7fff + ((u >> 16) & 1);            // RNE
    return (unsigned short)(u >> 16);
}

// 128x128 tile, K=256 (4 steps of BK=64), 512 threads = 8 waves (4m x 2n, 32x64 each).
// A: bf16 [m][k] row-major. B: [k][n] (BB16? bf16 : fp32), TRANS-staged to LDS [n][k].
// T2OUT: epilogue writes T2[b][x][z][j] (bz = batch) instead of C + bz*cBS.
template<bool BB16, bool T2OUT>
__global__ __launch_bounds__(512, 4)
void gemm_trans(const unsigned short* __restrict__ Ab, const void* __restrict__ Bbv,
                unsigned short* __restrict__ Cb,
                int lda, int ldb, int ldc,
                long aBS, int aSh, long bBS, long cBS)
{
    __shared__ unsigned short As[2][128 * LDST];
    __shared__ unsigned short Bs[2][128 * LDST];

    const int tid  = threadIdx.x;
    const int bz   = blockIdx.z;
    const int row0 = blockIdx.y * 128;
    const int col0 = blockIdx.x * 128;

    const unsigned short* Ah = Ab + (long)(bz >> aSh) * aBS;
    const float*          Bf = (const float*)Bbv          + (long)bz * bBS;
    const unsigned short* Bh = (const unsigned short*)Bbv + (long)bz * bBS;

    // staging indices
    const int ar  = tid >> 2;         // 0..127 A row
    const int akc = (tid & 3) * 16;   // A k-offset (16 elems = 2 x u16x8)
    const int kp  = (tid & 31) * 2;   // B k-row pair 0..62
    const int ng  = (tid >> 5) * 8;   // B n group of 8, 0..120

    // compute indices
    const int wid = tid >> 6, lane = tid & 63;
    const int wm = wid >> 1, wn = wid & 1;        // 4 m-waves x 2 n-waves
    const int lr = lane & 15, lg = lane >> 4;

    f32x4 acc[2][4] = {};

    // depth-2 prefetch sets (static-indexed: main loop fully unrolled)
    u16x8  aP[2][2];
    float4 bPf[2][4];
    u16x8  bPh[2][2];

    auto LOAD = [&](int set, int k0) {
        const unsigned short* p = Ah + (long)(row0 + ar) * lda + k0 + akc;
        aP[set][0] = *(const u16x8*)p;
        aP[set][1] = *(const u16x8*)(p + 8);
        if constexpr (!BB16) {
            const float* q = Bf + (long)(k0 + kp) * ldb + col0 + ng;
            bPf[set][0] = *(const float4*)q;
            bPf[set][1] = *(const float4*)(q + 4);
            bPf[set][2] = *(const float4*)(q + ldb);
            bPf[set][3] = *(const float4*)(q + ldb + 4);
        } else {
            const unsigned short* q = Bh + (long)(k0 + kp) * ldb + col0 + ng;
            bPh[set][0] = *(const u16x8*)q;
            bPh[set][1] = *(const u16x8*)(q + ldb);
        }
    };

    auto WRITE = [&](int set, int buf) {
        *(u16x8*)(As[buf] + ar * LDST + akc)     = aP[set][0];
        *(u16x8*)(As[buf] + ar * LDST + akc + 8) = aP[set][1];
#pragma unroll
        for (int e = 0; e < 8; ++e) {
            unsigned lo, hi;
            if constexpr (!BB16) {
                const float* v0 = (const float*)&bPf[set][0];  // k row kp   (8 floats)
                const float* v1 = (const float*)&bPf[set][2];  // k row kp+1 (8 floats)
                lo = f2bf(v0[e]); hi = f2bf(v1[e]);
            } else {
                lo = bPh[set][0][e]; hi = bPh[set][1][e];
            }
            *(unsigned*)(Bs[buf] + (ng + e) * LDST + kp) = lo | (hi << 16);
        }
    };

    auto COMPUTE = [&](int buf) {
#pragma unroll
        for (int kk = 0; kk < 2; ++kk) {
            bf16x8 aF[2], bF[4];
#pragma unroll
            for (int fm = 0; fm < 2; ++fm)
                aF[fm] = *(const bf16x8*)&As[buf][(wm * 32 + fm * 16 + lr) * LDST + kk * 32 + lg * 8];
#pragma unroll
            for (int fn = 0; fn < 4; ++fn)
                bF[fn] = *(const bf16x8*)&Bs[buf][(wn * 64 + fn * 16 + lr) * LDST + kk * 32 + lg * 8];
            __builtin_amdgcn_s_setprio(1);
#pragma unroll
            for (int fm = 0; fm < 2; ++fm)
#pragma unroll
                for (int fn = 0; fn < 4; ++fn)
                    acc[fm][fn] = __builtin_amdgcn_mfma_f32_16x16x32_bf16(
                        aF[fm], bF[fn], acc[fm][fn], 0, 0, 0);
            __builtin_amdgcn_s_setprio(0);
        }
    };

    LOAD(0, 0);
    WRITE(0, 0);        // one-time vmcnt stall; fills buf0
    LOAD(1, 64);        // set1 in flight across step 0
#pragma unroll
    for (int s = 0; s < 4; ++s) {
        asm volatile("s_waitcnt lgkmcnt(0)" ::: "memory");  // own ds ops drained
        __builtin_amdgcn_s_barrier();                       // no vmcnt drain
        if (s < 2) LOAD(s & 1, (s + 2) * 64);               // refill freed set
        COMPUTE(s & 1);
        if (s < 3) WRITE((s + 1) & 1, (s + 1) & 1);         // set loaded 1 step ago
    }

    // epilogue: C/D mapping col=lane&15, row=(lane>>4)*4+q  [m89-verified]
#pragma unroll
    for (int fm = 0; fm < 2; ++fm)
#pragma unroll
        for (int q = 0; q < 4; ++q) {
            const long row = row0 + wm * 32 + fm * 16 + lg * 4 + q;
#pragma unroll
            for (int fn = 0; fn < 4; ++fn) {
                const int col = col0 + wn * 64 + fn * 16 + lr;
                if constexpr (T2OUT) {
                    // T2[b][x=row][z=bz&15][j=col], b=bz>>4
                    unsigned short* Cq = Cb + (long)(bz >> 4) * 1048576 + (bz & 15) * 256;
                    Cq[row * 4096 + col] = f2bf(acc[fm][fn][q]);
                } else {
                    unsigned short* Cq = Cb + (long)bz * cBS;
                    Cq[row * (long)ldc + col] = f2bf(acc[fm][fn][q]);
                }
            }
        }
}

// Fused stage-3: out[b,x,y,z] = sum_j endbf[b,y,j] * T2[b,x,z,j]
// One block per (b, x-pair); 4 waves, wave w: y in [w*64, w*64+64).
// M=y(256) N=z(16, one fragment: z=lr) K=j(256). A-frags shared across both x.
__global__ __launch_bounds__(256)
void fused_out(const unsigned short* __restrict__ endbf,
               const unsigned short* __restrict__ T2,
               float* __restrict__ out)
{
    const int tid = threadIdx.x;
    const int b  = blockIdx.x >> 7;
    const int xp = blockIdx.x & 127;          // x-pair: x0=2*xp, x1=2*xp+1
    const int wid = tid >> 6, lane = tid & 63;
    const int lr = lane & 15, lg = lane >> 4;

    const unsigned short* Arow = endbf + (long)b * 65536;                       // [y][j]
    const unsigned short* B0 = T2 + ((long)(b * 256 + xp * 2) * 16 + lr) * 256; // [z=lr][j]
    const unsigned short* B1 = B0 + 4096;

    f32x4 acc0[4] = {}, acc1[4] = {};
    u16x8 a[2][4], pb0[2], pb1[2];

    auto LOADF = [&](int set, int k0) {
#pragma unroll
        for (int fm = 0; fm < 4; ++fm)
            a[set][fm] = *(const u16x8*)(Arow + (long)(wid * 64 + fm * 16 + lr) * 256 + k0 + lg * 8);
        pb0[set] = *(const u16x8*)(B0 + k0 + lg * 8);
        pb1[set] = *(const u16x8*)(B1 + k0 + lg * 8);
    };

    LOADF(0, 0);
#pragma unroll
    for (int s = 0; s < 8; ++s) {
        if (s < 7) LOADF((s + 1) & 1, (s + 1) * 32);
        __builtin_amdgcn_s_setprio(1);
#pragma unroll
        for (int fm = 0; fm < 4; ++fm) {
            acc0[fm] = __builtin_amdgcn_mfma_f32_16x16x32_bf16(
                __builtin_bit_cast(bf16x8, a[s & 1][fm]),
                __builtin_bit_cast(bf16x8, pb0[s & 1]), acc0[fm], 0, 0, 0);
            acc1[fm] = __builtin_amdgcn_mfma_f32_16x16x32_bf16(
                __builtin_bit_cast(bf16x8, a[s & 1][fm]),
                __builtin_bit_cast(bf16x8, pb1[s & 1]), acc1[fm], 0, 0, 0);
        }
        __builtin_amdgcn_s_setprio(0);
    }

    // D[m=y][n=z]: y = wid*64 + fm*16 + lg*4 + q, z = lr. out coalesced.
    float* op0 = out + (long)(b * 256 + xp * 2) * 4096;
    float* op1 = op0 + 4096;
#pragma unroll
    for (int fm = 0; fm < 4; ++fm)
#pragma unroll
        for (int q = 0; q < 4; ++q) {
            const int y = wid * 64 + fm * 16 + lg * 4 + q;
            op0[y * 16 + lr] = acc0[fm][q];
            op1[y * 16 + lr] = acc1[fm][q];
        }
}

// fp32 -> bf16: blocks 0..255 end, 256..511 start, 512..527 cls
__global__ __launch_bounds__(256)
void cvt_bf16(const float* __restrict__ endl, const float* __restrict__ start,
              const float* __restrict__ cls,
              unsigned short* __restrict__ endbf, unsigned short* __restrict__ startbf,
              unsigned short* __restrict__ clsbf)
{
    const int which = blockIdx.x >> 8;
    const float* in = which == 0 ? endl : (which == 1 ? start : cls);
    unsigned short* out = which == 0 ? endbf : (which == 1 ? startbf : clsbf);
    const int i = ((blockIdx.x & 255) * 256 + threadIdx.x) * 8;
    float4 v0 = *(const float4*)(in + i);
    float4 v1 = *(const float4*)(in + i + 4);
    const float* v = (const float*)&v0;
    u16x8 w;
#pragma unroll
    for (int e = 0; e < 4; ++e) w[e] = f2bf(v[e]);
    const float* u = (const float*)&v1;
#pragma unroll
    for (int e = 0; e < 4; ++e) w[4 + e] = f2bf(u[e]);
    *(u16x8*)(out + i) = w;
}

extern "C" void kernel_launch(void* const* d_in, const int* in_sizes, int n_in,
                              void* d_out, int out_size, void* d_ws, size_t ws_size,
                              hipStream_t stream)
{
    const float* start = (const float*)d_in[0];  // [8,256,256]
    const float* endl  = (const float*)d_in[1];  // [8,256,256]
    const float* cls   = (const float*)d_in[2];  // [8,16,256] -> [128][256]
    const float* W     = (const float*)d_in[3];  // [256,256,256] (i,o,j)
    float* out = (float*)d_out;                  // [8,256,256,16]

    char* ws = (char*)d_ws;
    unsigned short* Wc      = (unsigned short*)ws;                // bf16 [128][256][256]
    unsigned short* T2      = (unsigned short*)(ws + 16777216);   // bf16 [8][256][16][256]
    unsigned short* endbf   = (unsigned short*)(ws + 33554432);   // bf16 [8][256][256]
    unsigned short* startbf = (unsigned short*)(ws + 34603008);   // bf16 [8][256][256]
    unsigned short* clsbf   = (unsigned short*)(ws + 35651584);   // bf16 [128][256]

    // K0: end, start, cls -> bf16
    hipLaunchKernelGGL(cvt_bf16, dim3(528), dim3(256), 0, stream,
        endl, start, cls, endbf, startbf, clsbf);

    // K1: Wc[bz,i,j] = sum_o clsbf[bz,o]*W[i,o,j].  batch=i(256). M=128,N=256(j),K=256(o)
    //     A=clsbf bf16 (shared); B=W+i*65536 fp32 [o][j]; C=Wc+i*256 (ldc=65536, row=bz)
    hipLaunchKernelGGL((gemm_trans<false, false>), dim3(2, 1, 256), dim3(512), 0, stream,
        clsbf, (const void*)W, Wc, 256, 256, 65536, 0L, 0, 65536L, 256L);

    // K2: T2[b,x,z,j] = sum_i startbf[b,x,i]*Wc[bz,i,j].  batch=bz(128). M=N=K=256
    hipLaunchKernelGGL((gemm_trans<true, true>), dim3(2, 2, 128), dim3(512), 0, stream,
        startbf, (const void*)Wc, T2, 256, 256, 4096, 65536L, 4, 65536L, 0L);

    // K3': fused out (1024 blocks: b x 128 x-pairs)
    hipLaunchKernelGGL(fused_out, dim3(1024), dim3(256), 0, stream, endbf, T2, out);
}